// Round 20
// baseline (223.233 us; speedup 1.0000x reference)
//
#include <hip/hip_runtime.h>
#include <cstdint>
#include <cstddef>

typedef __bf16 bf16;
typedef __bf16 bf16x8 __attribute__((ext_vector_type(8)));
typedef __bf16 bf16x4 __attribute__((ext_vector_type(4)));
typedef __bf16 bf16x2 __attribute__((ext_vector_type(2)));
typedef float  f32x4  __attribute__((ext_vector_type(4)));
typedef float  f32x16 __attribute__((ext_vector_type(16)));
typedef int    i32x4  __attribute__((ext_vector_type(4)));

#define MFMA16(a, b, c) __builtin_amdgcn_mfma_f32_16x16x32_bf16((a), (b), (c), 0, 0, 0)
#define MFMA32(a, b, c) __builtin_amdgcn_mfma_f32_32x32x16_bf16((a), (b), (c), 0, 0, 0)

static constexpr int BB   = 4;
static constexpr int TT   = 2048;
static constexpr int DM   = 1024;
static constexpr int NH   = 16;
static constexpr int HD   = 64;
static constexpr int TOK  = BB * TT;    // 8192
static constexpr int NQKV = 3 * DM;     // 3072

// async global->LDS, 16B per lane; dst must be wave-uniform base (HW adds lane*16)
__device__ inline void gload16(const void* g, void* l) {
    __builtin_amdgcn_global_load_lds((const __attribute__((address_space(1))) void*)g,
                                     (__attribute__((address_space(3))) void*)l, 16, 0, 0);
}

// XOR-swizzle for [R][128B] row-major LDS tiles: spread each 16B column slot
// across 8 slots by row&7 (involution; preserves row bits >=7)
__device__ inline int swz(int x) { return x ^ ((x >> 3) & 0x70); }

// pack two f32 -> one dword of 2 bf16
__device__ inline int pk2(float a, float b) {
    bf16x2 t; t[0] = (bf16)a; t[1] = (bf16)b;
    return __builtin_bit_cast(int, t);
}

// ---------------- transpose + convert: in f32 [R][C] -> out bf16 [C][R] ----------------
__global__ void k_transpose_cvt(const float* __restrict__ in, bf16* __restrict__ out,
                                int R, int C) {
    __shared__ bf16 tl[64 * 72];
    int tid = threadIdx.x;
    int c0 = blockIdx.x * 64, r0 = blockIdx.y * 64;
#pragma unroll
    for (int rep = 0; rep < 4; rep++) {
        int r = rep * 16 + (tid >> 4);
        int c = (tid & 15) * 4;
        float4 v = *(const float4*)(in + (size_t)(r0 + r) * C + c0 + c);
        tl[r * 72 + c + 0] = (bf16)v.x;
        tl[r * 72 + c + 1] = (bf16)v.y;
        tl[r * 72 + c + 2] = (bf16)v.z;
        tl[r * 72 + c + 3] = (bf16)v.w;
    }
    __syncthreads();
#pragma unroll
    for (int rep = 0; rep < 4; rep++) {
        int cc = rep * 16 + (tid >> 4);
        int rr = (tid & 15) * 4;
        bf16x4 o;
        o[0] = tl[(rr + 0) * 72 + cc];
        o[1] = tl[(rr + 1) * 72 + cc];
        o[2] = tl[(rr + 2) * 72 + cc];
        o[3] = tl[(rr + 3) * 72 + cc];
        *(bf16x4*)(out + (size_t)(c0 + cc) * R + r0 + rr) = o;
    }
}

// ---------------- RoPE cos/sin table ----------------
__global__ void k_rope_tab(float* __restrict__ ct, float* __restrict__ st) {
    int i = blockIdx.x * blockDim.x + threadIdx.x;   // TT*32
    int t = i >> 5, j = i & 31;
    float invf = powf(10000.0f, -(float)j * (1.0f / 32.0f));
    float a = (float)t * invf;
    ct[i] = cosf(a);
    st[i] = sinf(a);
}

// ---------------- GEMM: C[M][N] = A[M][K] @ Bt[N][K]^T, f32 acc ----------------
// T2 conflict fix (swizzled LDS) + T3 minimum (dbuf, prefetch-before-compute,
// one barrier/K-step) + T1 XCD remap.
// MODE 1: A is f32 (x) — conversion FUSED into staging (replaces k_cvt):
//   loads issued at loop top (latency covered by compute), cvt+ds_write after
//   compute, before the barrier (T14 split). B staged via DMA from bf16.
//   Epilogue: fused-RoPE scatter -> qbuf/kbuf [B,H,T,64], vbuf [B,H,64,T].
// MODE 2: A is bf16 (ob), both matrices via DMA; f32 row-major out.
template <int MODE>
__global__ __launch_bounds__(256) void k_gemm_bt(
    const bf16* __restrict__ Abf, const float* __restrict__ Af,
    const bf16* __restrict__ Bt,
    int M, int N, int K,
    float* __restrict__ outF,
    bf16* __restrict__ qbuf, bf16* __restrict__ kbuf, bf16* __restrict__ vbuf,
    const float* __restrict__ ct, const float* __restrict__ st, float qscale) {
    __shared__ bf16 lA[2][128 * 64];   // [128 rows][128B], swizzled content
    __shared__ bf16 lB[2][128 * 64];
    int tid = threadIdx.x;
    int l = tid & 63, wid = tid >> 6;
    int wm = wid >> 1, wn = wid & 1;                 // 2x2 waves of 64x64
    // T1 XCD remap (bijective: nwg%8==0 for 1536 and 512)
    int NBN = gridDim.x;
    int flat = blockIdx.y * NBN + blockIdx.x;
    int q8 = (NBN * gridDim.y) >> 3;
    int nf = (flat & 7) * q8 + (flat >> 3);
    int bm = nf / NBN, bn = nf % NBN;
    const char* BbB = (const char*)(Bt + (size_t)bn * 128 * K);
    const size_t KB = (size_t)K * 2;                 // bf16 row stride in bytes
    f32x4 acc[4][4] = {};

    // B staging: LDS linear dest, swizzled global source (DMA)
#define GSTAGE_B(nb, kt) do {                                                              \
    _Pragma("unroll") for (int i = 0; i < 4; i++) {                                        \
        int cb = (wid * 4 + i) * 1024;                                                     \
        int Xs = swz(cb + l * 16);                                                         \
        gload16(BbB + (size_t)(Xs >> 7) * KB + (size_t)(kt) * 2 + (Xs & 127),              \
                (char*)lB[nb] + cb);                                                       \
    }                                                                                      \
} while (0)

    // A staging (MODE 2): DMA from bf16
#define GSTAGE_A2(nb, kt) do {                                                             \
    _Pragma("unroll") for (int i = 0; i < 4; i++) {                                        \
        int cb = (wid * 4 + i) * 1024;                                                     \
        int Xs = swz(cb + l * 16);                                                         \
        gload16(AbB + (size_t)(Xs >> 7) * KB + (size_t)(kt) * 2 + (Xs & 127),              \
                (char*)lA[nb] + cb);                                                       \
    }                                                                                      \
} while (0)

    int nsteps = K >> 6;
    int cur = 0;

    if (MODE == 1) {
        // reg-staged f32 A: lane covers row=tid>>1, 32-col half (tid&1)
        int arow = tid >> 1;
        int acolh = (tid & 1) * 32;                  // f32 col offset within slice
        const float* asrc = Af + (size_t)(bm * 128 + arow) * K + acolh;
        int awkey = (arow & 7) << 4;
        int awb0 = arow * 128 + acolh * 2;           // byte base in [row][128B] tile

        // prologue: stage slice 0 (A synchronously, B via DMA), one barrier
        {
            float4 av[8];
#pragma unroll
            for (int i = 0; i < 8; i++) av[i] = *(const float4*)(asrc + i * 4);
            GSTAGE_B(0, 0);
#pragma unroll
            for (int qd = 0; qd < 4; qd++) {
                i32x4 wv;
                wv[0] = pk2(av[2 * qd].x, av[2 * qd].y);
                wv[1] = pk2(av[2 * qd].z, av[2 * qd].w);
                wv[2] = pk2(av[2 * qd + 1].x, av[2 * qd + 1].y);
                wv[3] = pk2(av[2 * qd + 1].z, av[2 * qd + 1].w);
                *(i32x4*)((char*)lA[0] + ((awb0 + qd * 16) ^ awkey)) = wv;
            }
        }
        __syncthreads();
        for (int t = 0; t < nsteps; t++) {
            float4 av[8];
            if (t + 1 < nsteps) {
                int kt = (t + 1) << 6;
                GSTAGE_B(cur ^ 1, kt);               // B DMA prefetch
#pragma unroll
                for (int i = 0; i < 8; i++)          // A f32 loads (covered by compute)
                    av[i] = *(const float4*)(asrc + kt + i * 4);
            }
#pragma unroll
            for (int kk = 0; kk < 2; kk++) {
                bf16x8 af[4], bfr[4];
#pragma unroll
                for (int mi = 0; mi < 4; mi++) {
                    int rr = wm * 64 + mi * 16 + (l & 15);
                    int L = rr * 128 + (kk * 32 + (l >> 4) * 8) * 2;
                    af[mi] = *(const bf16x8*)((const char*)lA[cur] + swz(L));
                }
#pragma unroll
                for (int ni = 0; ni < 4; ni++) {
                    int rr = wn * 64 + ni * 16 + (l & 15);
                    int L = rr * 128 + (kk * 32 + (l >> 4) * 8) * 2;
                    bfr[ni] = *(const bf16x8*)((const char*)lB[cur] + swz(L));
                }
#pragma unroll
                for (int mi = 0; mi < 4; mi++)
#pragma unroll
                    for (int ni = 0; ni < 4; ni++)
                        acc[mi][ni] = MFMA16(af[mi], bfr[ni], acc[mi][ni]);
            }
            if (t + 1 < nsteps) {                    // cvt + write after compute (T14)
#pragma unroll
                for (int qd = 0; qd < 4; qd++) {
                    i32x4 wv;
                    wv[0] = pk2(av[2 * qd].x, av[2 * qd].y);
                    wv[1] = pk2(av[2 * qd].z, av[2 * qd].w);
                    wv[2] = pk2(av[2 * qd + 1].x, av[2 * qd + 1].y);
                    wv[3] = pk2(av[2 * qd + 1].z, av[2 * qd + 1].w);
                    *(i32x4*)((char*)lA[cur ^ 1] + ((awb0 + qd * 16) ^ awkey)) = wv;
                }
            }
            __syncthreads();                         // drains DMA + ds_writes
            cur ^= 1;
        }
    } else {
        const char* AbB = (const char*)(Abf + (size_t)bm * 128 * K);
        GSTAGE_A2(0, 0);
        GSTAGE_B(0, 0);
        __syncthreads();
        for (int t = 0; t < nsteps; t++) {
            if (t + 1 < nsteps) {
                GSTAGE_A2(cur ^ 1, (t + 1) << 6);
                GSTAGE_B(cur ^ 1, (t + 1) << 6);
            }
#pragma unroll
            for (int kk = 0; kk < 2; kk++) {
                bf16x8 af[4], bfr[4];
#pragma unroll
                for (int mi = 0; mi < 4; mi++) {
                    int rr = wm * 64 + mi * 16 + (l & 15);
                    int L = rr * 128 + (kk * 32 + (l >> 4) * 8) * 2;
                    af[mi] = *(const bf16x8*)((const char*)lA[cur] + swz(L));
                }
#pragma unroll
                for (int ni = 0; ni < 4; ni++) {
                    int rr = wn * 64 + ni * 16 + (l & 15);
                    int L = rr * 128 + (kk * 32 + (l >> 4) * 8) * 2;
                    bfr[ni] = *(const bf16x8*)((const char*)lB[cur] + swz(L));
                }
#pragma unroll
                for (int mi = 0; mi < 4; mi++)
#pragma unroll
                    for (int ni = 0; ni < 4; ni++)
                        acc[mi][ni] = MFMA16(af[mi], bfr[ni], acc[mi][ni]);
            }
            __syncthreads();
            cur ^= 1;
        }
    }
#undef GSTAGE_B
#undef GSTAGE_A2

    if (MODE == 2) {
#pragma unroll
        for (int mi = 0; mi < 4; mi++) {
            int m0 = bm * 128 + wm * 64 + mi * 16 + ((l >> 4) << 2);
#pragma unroll
            for (int ni = 0; ni < 4; ni++) {
                int n = bn * 128 + wn * 64 + ni * 16 + (l & 15);
#pragma unroll
                for (int rj = 0; rj < 4; rj++)
                    outF[(size_t)(m0 + rj) * N + n] = acc[mi][ni][rj];
            }
        }
    } else {
        int n0 = bn * 128 + wn * 64;                 // wave-uniform; 64-col span = one head
        int sQ = n0 >> 10;
        int h = (n0 & 1023) >> 6;
        if (sQ == 2) {                               // V: pre-transposed [B,H,64,T]
#pragma unroll
            for (int ni = 0; ni < 4; ni++) {
                int d = ni * 16 + (l & 15);
#pragma unroll
                for (int mi = 0; mi < 4; mi++) {
                    int m0 = bm * 128 + wm * 64 + mi * 16 + ((l >> 4) << 2);
                    int b = m0 >> 11, t0 = m0 & 2047;
                    bf16x4 pv;
#pragma unroll
                    for (int rj = 0; rj < 4; rj++) pv[rj] = (bf16)acc[mi][ni][rj];
                    *(bf16x4*)(vbuf + ((size_t)((b * NH + h) * HD + d)) * TT + t0) = pv;
                }
            }
        } else {                                     // Q/K: RoPE in f32, then scatter
            float qs = (sQ == 0) ? qscale : 1.0f;
            bf16* obuf = (sQ == 0) ? qbuf : kbuf;
#pragma unroll
            for (int mi = 0; mi < 4; mi++) {
                int m0 = bm * 128 + wm * 64 + mi * 16 + ((l >> 4) << 2);
                int b = m0 >> 11, t0 = m0 & 2047;
#pragma unroll
                for (int rj = 0; rj < 4; rj++) {
                    int t = t0 + rj;
                    bf16* dst = obuf + ((size_t)(b * NH + h) * TT + t) * HD;
                    const float* crow = ct + t * 32;
                    const float* srow = st + t * 32;
#pragma unroll
                    for (int ni2 = 0; ni2 < 2; ni2++) {
                        int d = ni2 * 16 + (l & 15);
                        float cs = crow[d], sn = srow[d];
                        float a  = acc[mi][ni2][rj];
                        float b2 = acc[mi][ni2 + 2][rj];
                        dst[d]      = (bf16)(qs * (a  * cs - b2 * sn));
                        dst[d + 32] = (bf16)(qs * (b2 * cs + a  * sn));
                    }
                }
            }
        }
    }
}

// ---------------- flash attention, round-17 structure (session best, verbatim) ----------------
// Q,K [B*H,T,64] (Q pre-scaled by log2e/sqrt(hd), both roped), Vt [B*H,64,T].
// Block (4 waves) owns a PAIR of 128-row q-strips (15-p, p): equal 34 units/wave.
// 2-WIDE PHASES: one barrier per 2 kv-units; K AND V tiles double-buffered via
// async DMA (r18 proved V-direct puts L2 latency on the critical path; staged V
// arrives fully overlapped). LDS 80KB, 2 blocks/CU.
// SWAPPED QK^T (verified r13-17): lane holds S^T, q=l&31 lane-local ->
// P writes are 16 pk2 + 8 ds_write_b64 at loop-invariant addr.
// Fixed-shift softmax (acc init -16, exp2); denominator via ones-MFMA.
// XCD remap keeps each bh's K/V L2-resident (FETCH ~29MB).
__global__ __launch_bounds__(256, 2) void k_attn(
    const bf16* __restrict__ Q, const bf16* __restrict__ K,
    const bf16* __restrict__ Vt, bf16* __restrict__ O) {
    __shared__ bf16 lK[2][2][4096];  // [dbuf][tile][64 kv x 64 d] swizzled, 8KB each
    __shared__ bf16 lV[2][2][4096];  // [dbuf][tile][64 d x 64 t] swizzled
    __shared__ bf16 lP[8192];        // [128 q][64 kv], stride 128B, XOR swizzled (16KB)
    int tid = threadIdx.x;
    int l = tid & 63, w = tid >> 6;
    // XCD-aware remap: grid (8,64); xcd = blockIdx.x; 8 bh per XCD
    int bx = blockIdx.x, by = blockIdx.y;
    int bh = bx * 8 + (by >> 3);
    int p = by & 7;                 // pair index 0..7
    const char* KbB = (const char*)(K + (size_t)bh * TT * HD);
    const char* VbB = (const char*)(Vt + (size_t)bh * HD * TT);
    int b = bh >> 4, h = bh & 15;

    bf16x8 ones;
#pragma unroll
    for (int e = 0; e < 8; e++) ones[e] = (bf16)1.0f;

    // loop-invariant P-write/read geometry: lane's lP row = w*32 + (l&31)
    int prow = w * 32 + (l & 31);
    int pwbase = prow * 128;            // byte base of the lane's row
    int pswzk = (prow & 7) << 4;        // row's XOR key
    int cbase = (l >> 5) * 8;           // byte sub-offset from lane-half kv interleave

// stage kv-tiles 2*ph and 2*ph+1 into buffer pair nb
#define STAGE2(nb, ph) do {                                                                \
    int X0_ = w * 1024 + l * 16;                                                           \
    int o0_ = swz(X0_), o1_ = swz(X0_ + 4096);                                             \
    _Pragma("unroll") for (int t_ = 0; t_ < 2; t_++) {                                     \
        int j_ = 2 * (ph) + t_;                                                            \
        const char* Kj_ = KbB + (size_t)j_ * 8192;                                         \
        gload16(Kj_ + o0_, (char*)lK[nb][t_] + w * 1024);                                  \
        gload16(Kj_ + o1_, (char*)lK[nb][t_] + w * 1024 + 4096);                           \
        gload16(VbB + (size_t)(o0_ >> 7) * (TT * 2) + (size_t)j_ * 128 + (o0_ & 127),      \
                (char*)lV[nb][t_] + w * 1024);                                             \
        gload16(VbB + (size_t)(o1_ >> 7) * (TT * 2) + (size_t)j_ * 128 + (o1_ & 127),      \
                (char*)lV[nb][t_] + w * 1024 + 4096);                                      \
    }                                                                                      \
} while (0)

// one kv-unit: QK^T(swapped) -> mask -> exp2 -> P(LDS) -> PV + denom
#define UNIT(cb, tt, jj) do {                                                              \
    f32x16 sc[2];                                                                          \
    _Pragma("unroll") for (int r = 0; r < 16; r++) { sc[0][r] = -16.0f; sc[1][r] = -16.0f; } \
    __builtin_amdgcn_s_setprio(1);                                                         \
    _Pragma("unroll") for (int kc = 0; kc < 4; kc++)                                       \
    _Pragma("unroll") for (int nj = 0; nj < 2; nj++) {                                     \
        int rr = nj * 32 + (l & 31);                                                       \
        int L = rr * 128 + ((kc * 16 + (l >> 5) * 8) * 2 ^ ((rr & 7) << 4));               \
        bf16x8 kb = *(const bf16x8*)((const char*)lK[cb][tt] + L);                         \
        sc[nj] = MFMA32(kb, qa[kc], sc[nj]);                                               \
    }                                                                                      \
    __builtin_amdgcn_s_setprio(0);                                                         \
    if ((jj) * 64 + 63 > wrow) {                                                           \
        int q_ = wrow + (l & 31);                                                          \
        _Pragma("unroll") for (int nj = 0; nj < 2; nj++)                                   \
        _Pragma("unroll") for (int r = 0; r < 16; r++) {                                   \
            int kvg = (jj) * 64 + nj * 32 + (r & 3) + 8 * (r >> 2) + 4 * (l >> 5);         \
            if (kvg > q_) sc[nj][r] = -1e30f;                                              \
        }                                                                                  \
    }                                                                                      \
    _Pragma("unroll") for (int nj = 0; nj < 2; nj++)                                       \
    _Pragma("unroll") for (int r = 0; r < 16; r++)                                         \
        sc[nj][r] = exp2f(sc[nj][r]);                                                      \
    _Pragma("unroll") for (int nj = 0; nj < 2; nj++)                                       \
    _Pragma("unroll") for (int qd = 0; qd < 4; qd++) {                                     \
        int2 v2;                                                                           \
        v2.x = pk2(sc[nj][qd * 4 + 0], sc[nj][qd * 4 + 1]);                                \
        v2.y = pk2(sc[nj][qd * 4 + 2], sc[nj][qd * 4 + 3]);                                \
        int col2 = nj * 64 + qd * 16 + cbase;                                              \
        *(int2*)((char*)lP + pwbase + (col2 ^ pswzk)) = v2;                                \
    }                                                                                      \
    __builtin_amdgcn_s_setprio(1);                                                         \
    _Pragma("unroll") for (int kc = 0; kc < 4; kc++) {                                     \
        bf16x8 pa = *(const bf16x8*)((const char*)lP + pwbase                              \
                     + ((kc * 32 + (l >> 5) * 16) ^ pswzk));                               \
        lacc = MFMA32(pa, ones, lacc);                                                     \
        _Pragma("unroll") for (int dt = 0; dt < 2; dt++) {                                 \
            int dd = dt * 32 + (l & 31);                                                   \
            int L = dd * 128 + ((kc * 16 + (l >> 5) * 8) * 2 ^ ((dd & 7) << 4));           \
            bf16x8 vbf = *(const bf16x8*)((const char*)lV[cb][tt] + L);                    \
            oacc[dt] = MFMA32(pa, vbf, oacc[dt]);                                          \
        }                                                                                  \
    }                                                                                      \
    __builtin_amdgcn_s_setprio(0);                                                         \
} while (0)

    for (int half = 0; half < 2; half++) {
        int s = (half == 0) ? (15 - p) : p;          // heavy strip first
        int r0 = s * 128;
        int nph = s + 1;                             // nblk = 2s+2 units = s+1 phases
        int wrow = r0 + w * 32;
        const bf16* Qb = Q + ((size_t)bh * TT + wrow) * HD;
        // Q B-fragments (col=q=l&31, k=d): same lane expression as an A-frag
        bf16x8 qa[4];
#pragma unroll
        for (int kc = 0; kc < 4; kc++)
            qa[kc] = *(const bf16x8*)(Qb + (size_t)(l & 31) * HD + kc * 16 + (l >> 5) * 8);

        f32x16 oacc[2] = {};
        f32x16 lacc = {};

        STAGE2(0, 0);
        __syncthreads();                             // buffer pair 0 ready
        int cur = 0;
        for (int ph = 0; ph < nph; ph++) {
            if (ph + 1 < nph) STAGE2(cur ^ 1, ph + 1);   // async prefetch under compute
            int j0 = 2 * ph;
            if (j0 * 64 <= wrow + 31) UNIT(cur, 0, j0);
            int j1 = 2 * ph + 1;
            if (j1 * 64 <= wrow + 31) UNIT(cur, 1, j1);
            __syncthreads();                         // drains STAGE2; next pair ready
            cur ^= 1;
        }
        // ---- epilogue: O[tok][h*64+d] bf16 (oacc: col=dd, row-regs=q) ----
#pragma unroll
        for (int r = 0; r < 16; r++) {
            int rq = (r & 3) + 8 * (r >> 2) + 4 * (l >> 5);
            int t = wrow + rq;
            float inv = 1.0f / lacc[r];
            size_t base = ((size_t)b * TT + t) * DM + h * HD;
#pragma unroll
            for (int dt = 0; dt < 2; dt++)
                O[base + dt * 32 + (l & 31)] = (bf16)(oacc[dt][r] * inv);
        }
    }
#undef STAGE2
#undef UNIT
}

extern "C" void kernel_launch(void* const* d_in, const int* in_sizes, int n_in,
                              void* d_out, int out_size, void* d_ws, size_t ws_size,
                              hipStream_t stream) {
    const float* x    = (const float*)d_in[0];
    const float* Wqkv = (const float*)d_in[1];
    const float* Wout = (const float*)d_in[2];
    float* out = (float*)d_out;

    char* ws = (char*)d_ws;
    size_t off = 0;
    auto alloc = [&](size_t bytes) {
        void* p = ws + off;
        off += (bytes + 255) & ~(size_t)255;
        return p;
    };
    bf16* wqkvt = (bf16*)alloc((size_t)NQKV * DM * 2);
    bf16* woutt = (bf16*)alloc((size_t)DM * DM * 2);
    bf16* qr    = (bf16*)alloc((size_t)TOK * DM * 2);
    bf16* kr    = (bf16*)alloc((size_t)TOK * DM * 2);
    bf16* vt    = (bf16*)alloc((size_t)TOK * DM * 2);
    bf16* ob    = (bf16*)alloc((size_t)TOK * DM * 2);
    float* ct   = (float*)alloc((size_t)TT * 32 * 4);
    float* st   = (float*)alloc((size_t)TT * 32 * 4);
    (void)ws_size; (void)in_sizes; (void)n_in; (void)out_size;

    k_transpose_cvt<<<dim3(NQKV / 64, DM / 64), 256, 0, stream>>>(Wqkv, wqkvt, DM, NQKV);
    k_transpose_cvt<<<dim3(DM / 64, DM / 64), 256, 0, stream>>>(Wout, woutt, DM, DM);
    k_rope_tab<<<TT * 32 / 256, 256, 0, stream>>>(ct, st);
    // Q scale folds 1/sqrt(64) * log2(e) so softmax runs in exp2 domain (applied in GEMM epilogue)
    // gemm1: A = x (f32, conversion fused in staging) — k_cvt eliminated
    k_gemm_bt<1><<<dim3(NQKV / 128, TOK / 128), 256, 0, stream>>>(
        nullptr, x, wqkvt, TOK, NQKV, DM, nullptr, qr, kr, vt,
        ct, st, 0.125f * 1.4426950408889634f);
    k_attn<<<dim3(8, 64), 256, 0, stream>>>(qr, kr, vt, ob);
    k_gemm_bt<2><<<dim3(DM / 128, TOK / 128), 256, 0, stream>>>(
        ob, nullptr, woutt, TOK, DM, DM, out, nullptr, nullptr, nullptr,
        nullptr, nullptr, 0.0f);
}

// Round 21
// 184.159 us; speedup vs baseline: 1.2122x; 1.2122x over previous
//
#include <hip/hip_runtime.h>
#include <cstdint>
#include <cstddef>

typedef __bf16 bf16;
typedef __bf16 bf16x8 __attribute__((ext_vector_type(8)));
typedef __bf16 bf16x4 __attribute__((ext_vector_type(4)));
typedef __bf16 bf16x2 __attribute__((ext_vector_type(2)));
typedef float  f32x4  __attribute__((ext_vector_type(4)));
typedef float  f32x16 __attribute__((ext_vector_type(16)));

#define MFMA16(a, b, c) __builtin_amdgcn_mfma_f32_16x16x32_bf16((a), (b), (c), 0, 0, 0)
#define MFMA32(a, b, c) __builtin_amdgcn_mfma_f32_32x32x16_bf16((a), (b), (c), 0, 0, 0)

static constexpr int BB   = 4;
static constexpr int TT   = 2048;
static constexpr int DM   = 1024;
static constexpr int NH   = 16;
static constexpr int HD   = 64;
static constexpr int TOK  = BB * TT;    // 8192
static constexpr int NQKV = 3 * DM;     // 3072

// async global->LDS, 16B per lane; dst must be wave-uniform base (HW adds lane*16)
__device__ inline void gload16(const void* g, void* l) {
    __builtin_amdgcn_global_load_lds((const __attribute__((address_space(1))) void*)g,
                                     (__attribute__((address_space(3))) void*)l, 16, 0, 0);
}

// XOR-swizzle for [R][128B] row-major LDS tiles: spread each 16B column slot
// across 8 slots by row&7 (involution; preserves row bits >=7)
__device__ inline int swz(int x) { return x ^ ((x >> 3) & 0x70); }

// pack two f32 -> one dword of 2 bf16
__device__ inline int pk2(float a, float b) {
    bf16x2 t; t[0] = (bf16)a; t[1] = (bf16)b;
    return __builtin_bit_cast(int, t);
}

// ---------------- elementwise f32 -> bf16 ----------------
__global__ void k_cvt(const float* __restrict__ in, bf16* __restrict__ out, int n) {
    int i = (blockIdx.x * blockDim.x + threadIdx.x) * 4;
    if (i >= n) return;
    float4 v = *(const float4*)(in + i);
    bf16x4 o;
    o[0] = (bf16)v.x; o[1] = (bf16)v.y; o[2] = (bf16)v.z; o[3] = (bf16)v.w;
    *(bf16x4*)(out + i) = o;
}

// ---------------- transpose + convert: in f32 [R][C] -> out bf16 [C][R] ----------------
__global__ void k_transpose_cvt(const float* __restrict__ in, bf16* __restrict__ out,
                                int R, int C) {
    __shared__ bf16 tl[64 * 72];
    int tid = threadIdx.x;
    int c0 = blockIdx.x * 64, r0 = blockIdx.y * 64;
#pragma unroll
    for (int rep = 0; rep < 4; rep++) {
        int r = rep * 16 + (tid >> 4);
        int c = (tid & 15) * 4;
        float4 v = *(const float4*)(in + (size_t)(r0 + r) * C + c0 + c);
        tl[r * 72 + c + 0] = (bf16)v.x;
        tl[r * 72 + c + 1] = (bf16)v.y;
        tl[r * 72 + c + 2] = (bf16)v.z;
        tl[r * 72 + c + 3] = (bf16)v.w;
    }
    __syncthreads();
#pragma unroll
    for (int rep = 0; rep < 4; rep++) {
        int cc = rep * 16 + (tid >> 4);
        int rr = (tid & 15) * 4;
        bf16x4 o;
        o[0] = tl[(rr + 0) * 72 + cc];
        o[1] = tl[(rr + 1) * 72 + cc];
        o[2] = tl[(rr + 2) * 72 + cc];
        o[3] = tl[(rr + 3) * 72 + cc];
        *(bf16x4*)(out + (size_t)(c0 + cc) * R + r0 + rr) = o;
    }
}

// ---------------- RoPE cos/sin table ----------------
__global__ void k_rope_tab(float* __restrict__ ct, float* __restrict__ st) {
    int i = blockIdx.x * blockDim.x + threadIdx.x;   // TT*32
    int t = i >> 5, j = i & 31;
    float invf = powf(10000.0f, -(float)j * (1.0f / 32.0f));
    float a = (float)t * invf;
    ct[i] = cosf(a);
    st[i] = sinf(a);
}

// ---------------- GEMM: C[M][N] = A[M][K] @ Bt[N][K]^T, bf16 in, f32 acc ----------------
// T2 conflict fix (pre-swizzled gload source + swz() ds_reads) + T3 minimum
// (double-buffered LDS, STAGE(next) before compute(cur), one barrier/K-step).
// T1 XCD-aware block remap (bm-major chunks per XCD). Bijective (nwg%8==0).
// MODE 1: fused-RoPE scatter epilogue -> qbuf/kbuf [B,H,T,64] (roped, Q pre-scaled),
//         vbuf [B,H,64,T]. Each wave's 64 n-cols = one head.
// MODE 2: f32 row-major out (final projection)
template <int MODE>
__global__ __launch_bounds__(256) void k_gemm_bt(
    const bf16* __restrict__ A, const bf16* __restrict__ Bt,
    int M, int N, int K,
    float* __restrict__ outF,
    bf16* __restrict__ qbuf, bf16* __restrict__ kbuf, bf16* __restrict__ vbuf,
    const float* __restrict__ ct, const float* __restrict__ st, float qscale) {
    __shared__ bf16 lA[2][128 * 64];   // [128 rows][128B], swizzled content
    __shared__ bf16 lB[2][128 * 64];
    int tid = threadIdx.x;
    int l = tid & 63, wid = tid >> 6;
    int wm = wid >> 1, wn = wid & 1;                 // 2x2 waves of 64x64
    // T1 XCD remap: dispatcher round-robins flat%8 across XCDs; give each XCD
    // a contiguous bm-major chunk so its L2 holds one A-panel + the B matrix.
    int NBN = gridDim.x;
    int flat = blockIdx.y * NBN + blockIdx.x;
    int q8 = (NBN * gridDim.y) >> 3;
    int nf = (flat & 7) * q8 + (flat >> 3);
    int bm = nf / NBN, bn = nf % NBN;
    const char* AbB = (const char*)(A + (size_t)bm * 128 * K);
    const char* BbB = (const char*)(Bt + (size_t)bn * 128 * K);
    const size_t KB = (size_t)K * 2;                 // global row stride in bytes
    f32x4 acc[4][4] = {};

    // stage one 64-col K-slice into buf nb: LDS linear dest, swizzled global source
#define GSTAGE(nb, kt) do {                                                                \
    _Pragma("unroll") for (int i = 0; i < 4; i++) {                                        \
        int cb = (wid * 4 + i) * 1024;               /* wave-uniform chunk base (8 rows) */\
        int Xs = swz(cb + l * 16);                   /* per-lane swizzled linear offset  */\
        gload16(AbB + (size_t)(Xs >> 7) * KB + (size_t)(kt) * 2 + (Xs & 127),              \
                (char*)lA[nb] + cb);                                                       \
        gload16(BbB + (size_t)(Xs >> 7) * KB + (size_t)(kt) * 2 + (Xs & 127),              \
                (char*)lB[nb] + cb);                                                       \
    }                                                                                      \
} while (0)

    GSTAGE(0, 0);
    __syncthreads();                                 // prologue drain
    int cur = 0;
    int nsteps = K >> 6;
    for (int t = 0; t < nsteps; t++) {
        if (t + 1 < nsteps) GSTAGE(cur ^ 1, (t + 1) << 6);   // prefetch under compute
#pragma unroll
        for (int kk = 0; kk < 2; kk++) {
            bf16x8 af[4], bfr[4];
#pragma unroll
            for (int mi = 0; mi < 4; mi++) {
                int rr = wm * 64 + mi * 16 + (l & 15);
                int L = rr * 128 + (kk * 32 + (l >> 4) * 8) * 2;
                af[mi] = *(const bf16x8*)((const char*)lA[cur] + swz(L));
            }
#pragma unroll
            for (int ni = 0; ni < 4; ni++) {
                int rr = wn * 64 + ni * 16 + (l & 15);
                int L = rr * 128 + (kk * 32 + (l >> 4) * 8) * 2;
                bfr[ni] = *(const bf16x8*)((const char*)lB[cur] + swz(L));
            }
#pragma unroll
            for (int mi = 0; mi < 4; mi++)
#pragma unroll
                for (int ni = 0; ni < 4; ni++)
                    acc[mi][ni] = MFMA16(af[mi], bfr[ni], acc[mi][ni]);
        }
        __syncthreads();                             // reads(cur) done + stage(cur^1) drained
        cur ^= 1;
    }
#undef GSTAGE

    if (MODE == 2) {
#pragma unroll
        for (int mi = 0; mi < 4; mi++) {
            int m0 = bm * 128 + wm * 64 + mi * 16 + ((l >> 4) << 2);
#pragma unroll
            for (int ni = 0; ni < 4; ni++) {
                int n = bn * 128 + wn * 64 + ni * 16 + (l & 15);
#pragma unroll
                for (int rj = 0; rj < 4; rj++)
                    outF[(size_t)(m0 + rj) * N + n] = acc[mi][ni][rj];
            }
        }
    } else {
        int n0 = bn * 128 + wn * 64;                 // wave-uniform; 64-col span = one head
        int sQ = n0 >> 10;
        int h = (n0 & 1023) >> 6;
        if (sQ == 2) {                               // V: pre-transposed [B,H,64,T]
#pragma unroll
            for (int ni = 0; ni < 4; ni++) {
                int d = ni * 16 + (l & 15);
#pragma unroll
                for (int mi = 0; mi < 4; mi++) {
                    int m0 = bm * 128 + wm * 64 + mi * 16 + ((l >> 4) << 2);
                    int b = m0 >> 11, t0 = m0 & 2047;
                    bf16x4 pv;
#pragma unroll
                    for (int rj = 0; rj < 4; rj++) pv[rj] = (bf16)acc[mi][ni][rj];
                    *(bf16x4*)(vbuf + ((size_t)((b * NH + h) * HD + d)) * TT + t0) = pv;
                }
            }
        } else {                                     // Q/K: RoPE in f32, then scatter
            float qs = (sQ == 0) ? qscale : 1.0f;
            bf16* obuf = (sQ == 0) ? qbuf : kbuf;
#pragma unroll
            for (int mi = 0; mi < 4; mi++) {
                int m0 = bm * 128 + wm * 64 + mi * 16 + ((l >> 4) << 2);
                int b = m0 >> 11, t0 = m0 & 2047;
#pragma unroll
                for (int rj = 0; rj < 4; rj++) {
                    int t = t0 + rj;
                    bf16* dst = obuf + ((size_t)(b * NH + h) * TT + t) * HD;
                    const float* crow = ct + t * 32;
                    const float* srow = st + t * 32;
#pragma unroll
                    for (int ni2 = 0; ni2 < 2; ni2++) {
                        int d = ni2 * 16 + (l & 15);
                        float cs = crow[d], sn = srow[d];
                        float a  = acc[mi][ni2][rj];
                        float b2 = acc[mi][ni2 + 2][rj];
                        dst[d]      = (bf16)(qs * (a  * cs - b2 * sn));
                        dst[d + 32] = (bf16)(qs * (b2 * cs + a  * sn));
                    }
                }
            }
        }
    }
}

// ---------------- flash attention, round-17 structure (session best, verbatim) ----------------
// Q,K [B*H,T,64] (Q pre-scaled by log2e/sqrt(hd), both roped), Vt [B*H,64,T].
// Block (4 waves) owns a PAIR of 128-row q-strips (15-p, p): equal 34 units/wave.
// 2-WIDE PHASES: one barrier per 2 kv-units; K AND V tiles double-buffered via
// async DMA (r18 proved V-direct puts L2 latency on the critical path; staged V
// arrives fully overlapped). LDS 80KB, 2 blocks/CU.
// SWAPPED QK^T (verified r13-17): lane holds S^T, q=l&31 lane-local ->
// P writes are 16 pk2 + 8 ds_write_b64 at loop-invariant addr.
// Fixed-shift softmax (acc init -16, exp2); denominator via ones-MFMA.
// XCD remap keeps each bh's K/V L2-resident (FETCH ~29MB).
__global__ __launch_bounds__(256, 2) void k_attn(
    const bf16* __restrict__ Q, const bf16* __restrict__ K,
    const bf16* __restrict__ Vt, bf16* __restrict__ O) {
    __shared__ bf16 lK[2][2][4096];  // [dbuf][tile][64 kv x 64 d] swizzled, 8KB each
    __shared__ bf16 lV[2][2][4096];  // [dbuf][tile][64 d x 64 t] swizzled
    __shared__ bf16 lP[8192];        // [128 q][64 kv], stride 128B, XOR swizzled (16KB)
    int tid = threadIdx.x;
    int l = tid & 63, w = tid >> 6;
    // XCD-aware remap: grid (8,64); xcd = blockIdx.x; 8 bh per XCD
    int bx = blockIdx.x, by = blockIdx.y;
    int bh = bx * 8 + (by >> 3);
    int p = by & 7;                 // pair index 0..7
    const char* KbB = (const char*)(K + (size_t)bh * TT * HD);
    const char* VbB = (const char*)(Vt + (size_t)bh * HD * TT);
    int b = bh >> 4, h = bh & 15;

    bf16x8 ones;
#pragma unroll
    for (int e = 0; e < 8; e++) ones[e] = (bf16)1.0f;

    // loop-invariant P-write/read geometry: lane's lP row = w*32 + (l&31)
    int prow = w * 32 + (l & 31);
    int pwbase = prow * 128;            // byte base of the lane's row
    int pswzk = (prow & 7) << 4;        // row's XOR key
    int cbase = (l >> 5) * 8;           // byte sub-offset from lane-half kv interleave

// stage kv-tiles 2*ph and 2*ph+1 into buffer pair nb
#define STAGE2(nb, ph) do {                                                                \
    int X0_ = w * 1024 + l * 16;                                                           \
    int o0_ = swz(X0_), o1_ = swz(X0_ + 4096);                                             \
    _Pragma("unroll") for (int t_ = 0; t_ < 2; t_++) {                                     \
        int j_ = 2 * (ph) + t_;                                                            \
        const char* Kj_ = KbB + (size_t)j_ * 8192;                                         \
        gload16(Kj_ + o0_, (char*)lK[nb][t_] + w * 1024);                                  \
        gload16(Kj_ + o1_, (char*)lK[nb][t_] + w * 1024 + 4096);                           \
        gload16(VbB + (size_t)(o0_ >> 7) * (TT * 2) + (size_t)j_ * 128 + (o0_ & 127),      \
                (char*)lV[nb][t_] + w * 1024);                                             \
        gload16(VbB + (size_t)(o1_ >> 7) * (TT * 2) + (size_t)j_ * 128 + (o1_ & 127),      \
                (char*)lV[nb][t_] + w * 1024 + 4096);                                      \
    }                                                                                      \
} while (0)

// one kv-unit: QK^T(swapped) -> mask -> exp2 -> P(LDS) -> PV + denom
#define UNIT(cb, tt, jj) do {                                                              \
    f32x16 sc[2];                                                                          \
    _Pragma("unroll") for (int r = 0; r < 16; r++) { sc[0][r] = -16.0f; sc[1][r] = -16.0f; } \
    __builtin_amdgcn_s_setprio(1);                                                         \
    _Pragma("unroll") for (int kc = 0; kc < 4; kc++)                                       \
    _Pragma("unroll") for (int nj = 0; nj < 2; nj++) {                                     \
        int rr = nj * 32 + (l & 31);                                                       \
        int L = rr * 128 + ((kc * 16 + (l >> 5) * 8) * 2 ^ ((rr & 7) << 4));               \
        bf16x8 kb = *(const bf16x8*)((const char*)lK[cb][tt] + L);                         \
        sc[nj] = MFMA32(kb, qa[kc], sc[nj]);                                               \
    }                                                                                      \
    __builtin_amdgcn_s_setprio(0);                                                         \
    if ((jj) * 64 + 63 > wrow) {                                                           \
        int q_ = wrow + (l & 31);                                                          \
        _Pragma("unroll") for (int nj = 0; nj < 2; nj++)                                   \
        _Pragma("unroll") for (int r = 0; r < 16; r++) {                                   \
            int kvg = (jj) * 64 + nj * 32 + (r & 3) + 8 * (r >> 2) + 4 * (l >> 5);         \
            if (kvg > q_) sc[nj][r] = -1e30f;                                              \
        }                                                                                  \
    }                                                                                      \
    _Pragma("unroll") for (int nj = 0; nj < 2; nj++)                                       \
    _Pragma("unroll") for (int r = 0; r < 16; r++)                                         \
        sc[nj][r] = exp2f(sc[nj][r]);                                                      \
    _Pragma("unroll") for (int nj = 0; nj < 2; nj++)                                       \
    _Pragma("unroll") for (int qd = 0; qd < 4; qd++) {                                     \
        int2 v2;                                                                           \
        v2.x = pk2(sc[nj][qd * 4 + 0], sc[nj][qd * 4 + 1]);                                \
        v2.y = pk2(sc[nj][qd * 4 + 2], sc[nj][qd * 4 + 3]);                                \
        int col2 = nj * 64 + qd * 16 + cbase;                                              \
        *(int2*)((char*)lP + pwbase + (col2 ^ pswzk)) = v2;                                \
    }                                                                                      \
    __builtin_amdgcn_s_setprio(1);                                                         \
    _Pragma("unroll") for (int kc = 0; kc < 4; kc++) {                                     \
        bf16x8 pa = *(const bf16x8*)((const char*)lP + pwbase                              \
                     + ((kc * 32 + (l >> 5) * 16) ^ pswzk));                               \
        lacc = MFMA32(pa, ones, lacc);                                                     \
        _Pragma("unroll") for (int dt = 0; dt < 2; dt++) {                                 \
            int dd = dt * 32 + (l & 31);                                                   \
            int L = dd * 128 + ((kc * 16 + (l >> 5) * 8) * 2 ^ ((dd & 7) << 4));           \
            bf16x8 vbf = *(const bf16x8*)((const char*)lV[cb][tt] + L);                    \
            oacc[dt] = MFMA32(pa, vbf, oacc[dt]);                                          \
        }                                                                                  \
    }                                                                                      \
    __builtin_amdgcn_s_setprio(0);                                                         \
} while (0)

    for (int half = 0; half < 2; half++) {
        int s = (half == 0) ? (15 - p) : p;          // heavy strip first
        int r0 = s * 128;
        int nph = s + 1;                             // nblk = 2s+2 units = s+1 phases
        int wrow = r0 + w * 32;
        const bf16* Qb = Q + ((size_t)bh * TT + wrow) * HD;
        // Q B-fragments (col=q=l&31, k=d): same lane expression as an A-frag
        bf16x8 qa[4];
#pragma unroll
        for (int kc = 0; kc < 4; kc++)
            qa[kc] = *(const bf16x8*)(Qb + (size_t)(l & 31) * HD + kc * 16 + (l >> 5) * 8);

        f32x16 oacc[2] = {};
        f32x16 lacc = {};

        STAGE2(0, 0);
        __syncthreads();                             // buffer pair 0 ready
        int cur = 0;
        for (int ph = 0; ph < nph; ph++) {
            if (ph + 1 < nph) STAGE2(cur ^ 1, ph + 1);   // async prefetch under compute
            int j0 = 2 * ph;
            if (j0 * 64 <= wrow + 31) UNIT(cur, 0, j0);
            int j1 = 2 * ph + 1;
            if (j1 * 64 <= wrow + 31) UNIT(cur, 1, j1);
            __syncthreads();                         // drains STAGE2; next pair ready
            cur ^= 1;
        }
        // ---- epilogue: O[tok][h*64+d] bf16 (oacc: col=dd, row-regs=q) ----
#pragma unroll
        for (int r = 0; r < 16; r++) {
            int rq = (r & 3) + 8 * (r >> 2) + 4 * (l >> 5);
            int t = wrow + rq;
            float inv = 1.0f / lacc[r];
            size_t base = ((size_t)b * TT + t) * DM + h * HD;
#pragma unroll
            for (int dt = 0; dt < 2; dt++)
                O[base + dt * 32 + (l & 31)] = (bf16)(oacc[dt][r] * inv);
        }
    }
#undef STAGE2
#undef UNIT
}

extern "C" void kernel_launch(void* const* d_in, const int* in_sizes, int n_in,
                              void* d_out, int out_size, void* d_ws, size_t ws_size,
                              hipStream_t stream) {
    const float* x    = (const float*)d_in[0];
    const float* Wqkv = (const float*)d_in[1];
    const float* Wout = (const float*)d_in[2];
    float* out = (float*)d_out;

    char* ws = (char*)d_ws;
    size_t off = 0;
    auto alloc = [&](size_t bytes) {
        void* p = ws + off;
        off += (bytes + 255) & ~(size_t)255;
        return p;
    };
    bf16* xb    = (bf16*)alloc((size_t)TOK * DM * 2);
    bf16* wqkvt = (bf16*)alloc((size_t)NQKV * DM * 2);
    bf16* woutt = (bf16*)alloc((size_t)DM * DM * 2);
    bf16* qr    = (bf16*)alloc((size_t)TOK * DM * 2);
    bf16* kr    = (bf16*)alloc((size_t)TOK * DM * 2);
    bf16* vt    = (bf16*)alloc((size_t)TOK * DM * 2);
    bf16* ob    = (bf16*)alloc((size_t)TOK * DM * 2);
    float* ct   = (float*)alloc((size_t)TT * 32 * 4);
    float* st   = (float*)alloc((size_t)TT * 32 * 4);
    (void)ws_size; (void)in_sizes; (void)n_in; (void)out_size;

    k_cvt<<<TOK * DM / 4 / 256, 256, 0, stream>>>(x, xb, TOK * DM);
    k_transpose_cvt<<<dim3(NQKV / 64, DM / 64), 256, 0, stream>>>(Wqkv, wqkvt, DM, NQKV);
    k_transpose_cvt<<<dim3(DM / 64, DM / 64), 256, 0, stream>>>(Wout, woutt, DM, DM);
    k_rope_tab<<<TT * 32 / 256, 256, 0, stream>>>(ct, st);
    // Q scale folds 1/sqrt(64) * log2(e) so softmax runs in exp2 domain (applied in GEMM epilogue)
    k_gemm_bt<1><<<dim3(NQKV / 128, TOK / 128), 256, 0, stream>>>(
        xb, wqkvt, TOK, NQKV, DM, nullptr, qr, kr, vt,
        ct, st, 0.125f * 1.4426950408889634f);
    k_attn<<<dim3(8, 64), 256, 0, stream>>>(qr, kr, vt, ob);
    k_gemm_bt<2><<<dim3(DM / 128, TOK / 128), 256, 0, stream>>>(
        ob, woutt, TOK, DM, DM, out, nullptr, nullptr, nullptr,
        nullptr, nullptr, 0.0f);
}

// Round 22
// 183.350 us; speedup vs baseline: 1.2175x; 1.0044x over previous
//
#include <hip/hip_runtime.h>
#include <cstdint>
#include <cstddef>

typedef __bf16 bf16;
typedef __bf16 bf16x8 __attribute__((ext_vector_type(8)));
typedef __bf16 bf16x4 __attribute__((ext_vector_type(4)));
typedef __bf16 bf16x2 __attribute__((ext_vector_type(2)));
typedef float  f32x4  __attribute__((ext_vector_type(4)));
typedef float  f32x16 __attribute__((ext_vector_type(16)));

#define MFMA16(a, b, c) __builtin_amdgcn_mfma_f32_16x16x32_bf16((a), (b), (c), 0, 0, 0)
#define MFMA32(a, b, c) __builtin_amdgcn_mfma_f32_32x32x16_bf16((a), (b), (c), 0, 0, 0)

static constexpr int BB   = 4;
static constexpr int TT   = 2048;
static constexpr int DM   = 1024;
static constexpr int NH   = 16;
static constexpr int HD   = 64;
static constexpr int TOK  = BB * TT;    // 8192
static constexpr int NQKV = 3 * DM;     // 3072

// async global->LDS, 16B per lane; dst must be wave-uniform base (HW adds lane*16)
__device__ inline void gload16(const void* g, void* l) {
    __builtin_amdgcn_global_load_lds((const __attribute__((address_space(1))) void*)g,
                                     (__attribute__((address_space(3))) void*)l, 16, 0, 0);
}

// XOR-swizzle for [R][128B] row-major LDS tiles: spread each 16B column slot
// across 8 slots by row&7 (involution; preserves row bits >=7)
__device__ inline int swz(int x) { return x ^ ((x >> 3) & 0x70); }

// pack two f32 -> one dword of 2 bf16
__device__ inline int pk2(float a, float b) {
    bf16x2 t; t[0] = (bf16)a; t[1] = (bf16)b;
    return __builtin_bit_cast(int, t);
}

// ---------------- elementwise f32 -> bf16 ----------------
__global__ void k_cvt(const float* __restrict__ in, bf16* __restrict__ out, int n) {
    int i = (blockIdx.x * blockDim.x + threadIdx.x) * 4;
    if (i >= n) return;
    float4 v = *(const float4*)(in + i);
    bf16x4 o;
    o[0] = (bf16)v.x; o[1] = (bf16)v.y; o[2] = (bf16)v.z; o[3] = (bf16)v.w;
    *(bf16x4*)(out + i) = o;
}

// ---------------- transpose + convert: in f32 [R][C] -> out bf16 [C][R] ----------------
__global__ void k_transpose_cvt(const float* __restrict__ in, bf16* __restrict__ out,
                                int R, int C) {
    __shared__ bf16 tl[64 * 72];
    int tid = threadIdx.x;
    int c0 = blockIdx.x * 64, r0 = blockIdx.y * 64;
#pragma unroll
    for (int rep = 0; rep < 4; rep++) {
        int r = rep * 16 + (tid >> 4);
        int c = (tid & 15) * 4;
        float4 v = *(const float4*)(in + (size_t)(r0 + r) * C + c0 + c);
        tl[r * 72 + c + 0] = (bf16)v.x;
        tl[r * 72 + c + 1] = (bf16)v.y;
        tl[r * 72 + c + 2] = (bf16)v.z;
        tl[r * 72 + c + 3] = (bf16)v.w;
    }
    __syncthreads();
#pragma unroll
    for (int rep = 0; rep < 4; rep++) {
        int cc = rep * 16 + (tid >> 4);
        int rr = (tid & 15) * 4;
        bf16x4 o;
        o[0] = tl[(rr + 0) * 72 + cc];
        o[1] = tl[(rr + 1) * 72 + cc];
        o[2] = tl[(rr + 2) * 72 + cc];
        o[3] = tl[(rr + 3) * 72 + cc];
        *(bf16x4*)(out + (size_t)(c0 + cc) * R + r0 + rr) = o;
    }
}

// ---------------- RoPE cos/sin table ----------------
__global__ void k_rope_tab(float* __restrict__ ct, float* __restrict__ st) {
    int i = blockIdx.x * blockDim.x + threadIdx.x;   // TT*32
    int t = i >> 5, j = i & 31;
    float invf = powf(10000.0f, -(float)j * (1.0f / 32.0f));
    float a = (float)t * invf;
    ct[i] = cosf(a);
    st[i] = sinf(a);
}

// ---------------- GEMM: C[M][N] = A[M][K] @ Bt[N][K]^T, bf16 in, f32 acc ----------------
// T2 conflict fix (pre-swizzled gload source + swz() ds_reads) + T3 minimum
// (double-buffered LDS, STAGE(next) before compute(cur), one barrier/K-step).
// T1 XCD-aware block remap (bm-major chunks per XCD). Bijective (nwg%8==0).
// MODE 1: fused-RoPE scatter epilogue -> qbuf/kbuf [B,H,T,64] (roped, Q pre-scaled),
//         vbuf [B,H,64,T]. Each wave's 64 n-cols = one head.
// MODE 2: f32 row-major out (final projection)
template <int MODE>
__global__ __launch_bounds__(256) void k_gemm_bt(
    const bf16* __restrict__ A, const bf16* __restrict__ Bt,
    int M, int N, int K,
    float* __restrict__ outF,
    bf16* __restrict__ qbuf, bf16* __restrict__ kbuf, bf16* __restrict__ vbuf,
    const float* __restrict__ ct, const float* __restrict__ st, float qscale) {
    __shared__ bf16 lA[2][128 * 64];   // [128 rows][128B], swizzled content
    __shared__ bf16 lB[2][128 * 64];
    int tid = threadIdx.x;
    int l = tid & 63, wid = tid >> 6;
    int wm = wid >> 1, wn = wid & 1;                 // 2x2 waves of 64x64
    // T1 XCD remap: dispatcher round-robins flat%8 across XCDs; give each XCD
    // a contiguous bm-major chunk so its L2 holds one A-panel + the B matrix.
    int NBN = gridDim.x;
    int flat = blockIdx.y * NBN + blockIdx.x;
    int q8 = (NBN * gridDim.y) >> 3;
    int nf = (flat & 7) * q8 + (flat >> 3);
    int bm = nf / NBN, bn = nf % NBN;
    const char* AbB = (const char*)(A + (size_t)bm * 128 * K);
    const char* BbB = (const char*)(Bt + (size_t)bn * 128 * K);
    const size_t KB = (size_t)K * 2;                 // global row stride in bytes
    f32x4 acc[4][4] = {};

    // stage one 64-col K-slice into buf nb: LDS linear dest, swizzled global source
#define GSTAGE(nb, kt) do {                                                                \
    _Pragma("unroll") for (int i = 0; i < 4; i++) {                                        \
        int cb = (wid * 4 + i) * 1024;               /* wave-uniform chunk base (8 rows) */\
        int Xs = swz(cb + l * 16);                   /* per-lane swizzled linear offset  */\
        gload16(AbB + (size_t)(Xs >> 7) * KB + (size_t)(kt) * 2 + (Xs & 127),              \
                (char*)lA[nb] + cb);                                                       \
        gload16(BbB + (size_t)(Xs >> 7) * KB + (size_t)(kt) * 2 + (Xs & 127),              \
                (char*)lB[nb] + cb);                                                       \
    }                                                                                      \
} while (0)

    GSTAGE(0, 0);
    __syncthreads();                                 // prologue drain
    int cur = 0;
    int nsteps = K >> 6;
    for (int t = 0; t < nsteps; t++) {
        if (t + 1 < nsteps) GSTAGE(cur ^ 1, (t + 1) << 6);   // prefetch under compute
#pragma unroll
        for (int kk = 0; kk < 2; kk++) {
            bf16x8 af[4], bfr[4];
#pragma unroll
            for (int mi = 0; mi < 4; mi++) {
                int rr = wm * 64 + mi * 16 + (l & 15);
                int L = rr * 128 + (kk * 32 + (l >> 4) * 8) * 2;
                af[mi] = *(const bf16x8*)((const char*)lA[cur] + swz(L));
            }
#pragma unroll
            for (int ni = 0; ni < 4; ni++) {
                int rr = wn * 64 + ni * 16 + (l & 15);
                int L = rr * 128 + (kk * 32 + (l >> 4) * 8) * 2;
                bfr[ni] = *(const bf16x8*)((const char*)lB[cur] + swz(L));
            }
#pragma unroll
            for (int mi = 0; mi < 4; mi++)
#pragma unroll
                for (int ni = 0; ni < 4; ni++)
                    acc[mi][ni] = MFMA16(af[mi], bfr[ni], acc[mi][ni]);
        }
        __syncthreads();                             // reads(cur) done + stage(cur^1) drained
        cur ^= 1;
    }
#undef GSTAGE

    if (MODE == 2) {
#pragma unroll
        for (int mi = 0; mi < 4; mi++) {
            int m0 = bm * 128 + wm * 64 + mi * 16 + ((l >> 4) << 2);
#pragma unroll
            for (int ni = 0; ni < 4; ni++) {
                int n = bn * 128 + wn * 64 + ni * 16 + (l & 15);
#pragma unroll
                for (int rj = 0; rj < 4; rj++)
                    outF[(size_t)(m0 + rj) * N + n] = acc[mi][ni][rj];
            }
        }
    } else {
        int n0 = bn * 128 + wn * 64;                 // wave-uniform; 64-col span = one head
        int sQ = n0 >> 10;
        int h = (n0 & 1023) >> 6;
        if (sQ == 2) {                               // V: pre-transposed [B,H,64,T]
#pragma unroll
            for (int ni = 0; ni < 4; ni++) {
                int d = ni * 16 + (l & 15);
#pragma unroll
                for (int mi = 0; mi < 4; mi++) {
                    int m0 = bm * 128 + wm * 64 + mi * 16 + ((l >> 4) << 2);
                    int b = m0 >> 11, t0 = m0 & 2047;
                    bf16x4 pv;
#pragma unroll
                    for (int rj = 0; rj < 4; rj++) pv[rj] = (bf16)acc[mi][ni][rj];
                    *(bf16x4*)(vbuf + ((size_t)((b * NH + h) * HD + d)) * TT + t0) = pv;
                }
            }
        } else {                                     // Q/K: RoPE in f32, then scatter
            float qs = (sQ == 0) ? qscale : 1.0f;
            bf16* obuf = (sQ == 0) ? qbuf : kbuf;
#pragma unroll
            for (int mi = 0; mi < 4; mi++) {
                int m0 = bm * 128 + wm * 64 + mi * 16 + ((l >> 4) << 2);
                int b = m0 >> 11, t0 = m0 & 2047;
#pragma unroll
                for (int rj = 0; rj < 4; rj++) {
                    int t = t0 + rj;
                    bf16* dst = obuf + ((size_t)(b * NH + h) * TT + t) * HD;
                    const float* crow = ct + t * 32;
                    const float* srow = st + t * 32;
#pragma unroll
                    for (int ni2 = 0; ni2 < 2; ni2++) {
                        int d = ni2 * 16 + (l & 15);
                        float cs = crow[d], sn = srow[d];
                        float a  = acc[mi][ni2][rj];
                        float b2 = acc[mi][ni2 + 2][rj];
                        dst[d]      = (bf16)(qs * (a  * cs - b2 * sn));
                        dst[d + 32] = (bf16)(qs * (b2 * cs + a  * sn));
                    }
                }
            }
        }
    }
}

// ---------------- flash attention, round-17 structure + const-C acc init ----------------
// Q,K [B*H,T,64] (Q pre-scaled by log2e/sqrt(hd), both roped), Vt [B*H,64,T].
// Block (4 waves) owns a PAIR of 128-row q-strips (15-p, p): equal 34 units/wave.
// 2-WIDE PHASES: one barrier per 2 kv-units; K AND V tiles double-buffered via
// async DMA. LDS 80KB, 2 blocks/CU.
// SWAPPED QK^T: lane holds S^T, q=l&31 lane-local -> P writes are 16 pk2 +
// 8 ds_write_b64 at loop-invariant addr.
// Round-22: first QK MFMA of each unit takes a LOOP-INVARIANT f32x16 const
// (-16) as its C operand -> removes 32 v_mov acc-init per unit per lane
// (attn is VALU-limited: 48% VALU vs 23% MFMA). Numerically identical.
// Fixed-shift softmax (exp2 domain); denominator via ones-MFMA.
// XCD remap keeps each bh's K/V L2-resident (FETCH ~29MB).
__global__ __launch_bounds__(256, 2) void k_attn(
    const bf16* __restrict__ Q, const bf16* __restrict__ K,
    const bf16* __restrict__ Vt, bf16* __restrict__ O) {
    __shared__ bf16 lK[2][2][4096];  // [dbuf][tile][64 kv x 64 d] swizzled, 8KB each
    __shared__ bf16 lV[2][2][4096];  // [dbuf][tile][64 d x 64 t] swizzled
    __shared__ bf16 lP[8192];        // [128 q][64 kv], stride 128B, XOR swizzled (16KB)
    int tid = threadIdx.x;
    int l = tid & 63, w = tid >> 6;
    // XCD-aware remap: grid (8,64); xcd = blockIdx.x; 8 bh per XCD
    int bx = blockIdx.x, by = blockIdx.y;
    int bh = bx * 8 + (by >> 3);
    int p = by & 7;                 // pair index 0..7
    const char* KbB = (const char*)(K + (size_t)bh * TT * HD);
    const char* VbB = (const char*)(Vt + (size_t)bh * HD * TT);
    int b = bh >> 4, h = bh & 15;

    bf16x8 ones;
#pragma unroll
    for (int e = 0; e < 8; e++) ones[e] = (bf16)1.0f;
    f32x16 m16;                      // loop-invariant fixed-shift C operand
#pragma unroll
    for (int r = 0; r < 16; r++) m16[r] = -16.0f;

    // loop-invariant P-write/read geometry: lane's lP row = w*32 + (l&31)
    int prow = w * 32 + (l & 31);
    int pwbase = prow * 128;            // byte base of the lane's row
    int pswzk = (prow & 7) << 4;        // row's XOR key
    int cbase = (l >> 5) * 8;           // byte sub-offset from lane-half kv interleave

// stage kv-tiles 2*ph and 2*ph+1 into buffer pair nb
#define STAGE2(nb, ph) do {                                                                \
    int X0_ = w * 1024 + l * 16;                                                           \
    int o0_ = swz(X0_), o1_ = swz(X0_ + 4096);                                             \
    _Pragma("unroll") for (int t_ = 0; t_ < 2; t_++) {                                     \
        int j_ = 2 * (ph) + t_;                                                            \
        const char* Kj_ = KbB + (size_t)j_ * 8192;                                         \
        gload16(Kj_ + o0_, (char*)lK[nb][t_] + w * 1024);                                  \
        gload16(Kj_ + o1_, (char*)lK[nb][t_] + w * 1024 + 4096);                           \
        gload16(VbB + (size_t)(o0_ >> 7) * (TT * 2) + (size_t)j_ * 128 + (o0_ & 127),      \
                (char*)lV[nb][t_] + w * 1024);                                             \
        gload16(VbB + (size_t)(o1_ >> 7) * (TT * 2) + (size_t)j_ * 128 + (o1_ & 127),      \
                (char*)lV[nb][t_] + w * 1024 + 4096);                                      \
    }                                                                                      \
} while (0)

// one kv-unit: QK^T(swapped, const-C init) -> mask -> exp2 -> P(LDS) -> PV + denom
#define UNIT(cb, tt, jj) do {                                                              \
    f32x16 sc[2];                                                                          \
    __builtin_amdgcn_s_setprio(1);                                                         \
    _Pragma("unroll") for (int kc = 0; kc < 4; kc++)                                       \
    _Pragma("unroll") for (int nj = 0; nj < 2; nj++) {                                     \
        int rr = nj * 32 + (l & 31);                                                       \
        int L = rr * 128 + ((kc * 16 + (l >> 5) * 8) * 2 ^ ((rr & 7) << 4));               \
        bf16x8 kb = *(const bf16x8*)((const char*)lK[cb][tt] + L);                         \
        sc[nj] = MFMA32(kb, qa[kc], (kc == 0) ? m16 : sc[nj]);                             \
    }                                                                                      \
    __builtin_amdgcn_s_setprio(0);                                                         \
    if ((jj) * 64 + 63 > wrow) {                                                           \
        int q_ = wrow + (l & 31);                                                          \
        _Pragma("unroll") for (int nj = 0; nj < 2; nj++)                                   \
        _Pragma("unroll") for (int r = 0; r < 16; r++) {                                   \
            int kvg = (jj) * 64 + nj * 32 + (r & 3) + 8 * (r >> 2) + 4 * (l >> 5);         \
            if (kvg > q_) sc[nj][r] = -1e30f;                                              \
        }                                                                                  \
    }                                                                                      \
    _Pragma("unroll") for (int nj = 0; nj < 2; nj++)                                       \
    _Pragma("unroll") for (int r = 0; r < 16; r++)                                         \
        sc[nj][r] = exp2f(sc[nj][r]);                                                      \
    _Pragma("unroll") for (int nj = 0; nj < 2; nj++)                                       \
    _Pragma("unroll") for (int qd = 0; qd < 4; qd++) {                                     \
        int2 v2;                                                                           \
        v2.x = pk2(sc[nj][qd * 4 + 0], sc[nj][qd * 4 + 1]);                                \
        v2.y = pk2(sc[nj][qd * 4 + 2], sc[nj][qd * 4 + 3]);                                \
        int col2 = nj * 64 + qd * 16 + cbase;                                              \
        *(int2*)((char*)lP + pwbase + (col2 ^ pswzk)) = v2;                                \
    }                                                                                      \
    __builtin_amdgcn_s_setprio(1);                                                         \
    _Pragma("unroll") for (int kc = 0; kc < 4; kc++) {                                     \
        bf16x8 pa = *(const bf16x8*)((const char*)lP + pwbase                              \
                     + ((kc * 32 + (l >> 5) * 16) ^ pswzk));                               \
        lacc = MFMA32(pa, ones, lacc);                                                     \
        _Pragma("unroll") for (int dt = 0; dt < 2; dt++) {                                 \
            int dd = dt * 32 + (l & 31);                                                   \
            int L = dd * 128 + ((kc * 16 + (l >> 5) * 8) * 2 ^ ((dd & 7) << 4));           \
            bf16x8 vbf = *(const bf16x8*)((const char*)lV[cb][tt] + L);                    \
            oacc[dt] = MFMA32(pa, vbf, oacc[dt]);                                          \
        }                                                                                  \
    }                                                                                      \
    __builtin_amdgcn_s_setprio(0);                                                         \
} while (0)

    for (int half = 0; half < 2; half++) {
        int s = (half == 0) ? (15 - p) : p;          // heavy strip first
        int r0 = s * 128;
        int nph = s + 1;                             // nblk = 2s+2 units = s+1 phases
        int wrow = r0 + w * 32;
        const bf16* Qb = Q + ((size_t)bh * TT + wrow) * HD;
        // Q B-fragments (col=q=l&31, k=d): same lane expression as an A-frag
        bf16x8 qa[4];
#pragma unroll
        for (int kc = 0; kc < 4; kc++)
            qa[kc] = *(const bf16x8*)(Qb + (size_t)(l & 31) * HD + kc * 16 + (l >> 5) * 8);

        f32x16 oacc[2] = {};
        f32x16 lacc = {};

        STAGE2(0, 0);
        __syncthreads();                             // buffer pair 0 ready
        int cur = 0;
        for (int ph = 0; ph < nph; ph++) {
            if (ph + 1 < nph) STAGE2(cur ^ 1, ph + 1);   // async prefetch under compute
            int j0 = 2 * ph;
            if (j0 * 64 <= wrow + 31) UNIT(cur, 0, j0);
            int j1 = 2 * ph + 1;
            if (j1 * 64 <= wrow + 31) UNIT(cur, 1, j1);
            __syncthreads();                         // drains STAGE2; next pair ready
            cur ^= 1;
        }
        // ---- epilogue: O[tok][h*64+d] bf16 (oacc: col=dd, row-regs=q) ----
#pragma unroll
        for (int r = 0; r < 16; r++) {
            int rq = (r & 3) + 8 * (r >> 2) + 4 * (l >> 5);
            int t = wrow + rq;
            float inv = 1.0f / lacc[r];
            size_t base = ((size_t)b * TT + t) * DM + h * HD;
#pragma unroll
            for (int dt = 0; dt < 2; dt++)
                O[base + dt * 32 + (l & 31)] = (bf16)(oacc[dt][r] * inv);
        }
    }
#undef STAGE2
#undef UNIT
}

extern "C" void kernel_launch(void* const* d_in, const int* in_sizes, int n_in,
                              void* d_out, int out_size, void* d_ws, size_t ws_size,
                              hipStream_t stream) {
    const float* x    = (const float*)d_in[0];
    const float* Wqkv = (const float*)d_in[1];
    const float* Wout = (const float*)d_in[2];
    float* out = (float*)d_out;

    char* ws = (char*)d_ws;
    size_t off = 0;
    auto alloc = [&](size_t bytes) {
        void* p = ws + off;
        off += (bytes + 255) & ~(size_t)255;
        return p;
    };
    bf16* xb    = (bf16*)alloc((size_t)TOK * DM * 2);
    bf16* wqkvt = (bf16*)alloc((size_t)NQKV * DM * 2);
    bf16* woutt = (bf16*)alloc((size_t)DM * DM * 2);
    bf16* qr    = (bf16*)alloc((size_t)TOK * DM * 2);
    bf16* kr    = (bf16*)alloc((size_t)TOK * DM * 2);
    bf16* vt    = (bf16*)alloc((size_t)TOK * DM * 2);
    bf16* ob    = (bf16*)alloc((size_t)TOK * DM * 2);
    float* ct   = (float*)alloc((size_t)TT * 32 * 4);
    float* st   = (float*)alloc((size_t)TT * 32 * 4);
    (void)ws_size; (void)in_sizes; (void)n_in; (void)out_size;

    k_cvt<<<TOK * DM / 4 / 256, 256, 0, stream>>>(x, xb, TOK * DM);
    k_transpose_cvt<<<dim3(NQKV / 64, DM / 64), 256, 0, stream>>>(Wqkv, wqkvt, DM, NQKV);
    k_transpose_cvt<<<dim3(DM / 64, DM / 64), 256, 0, stream>>>(Wout, woutt, DM, DM);
    k_rope_tab<<<TT * 32 / 256, 256, 0, stream>>>(ct, st);
    // Q scale folds 1/sqrt(64) * log2(e) so softmax runs in exp2 domain (applied in GEMM epilogue)
    k_gemm_bt<1><<<dim3(NQKV / 128, TOK / 128), 256, 0, stream>>>(
        xb, wqkvt, TOK, NQKV, DM, nullptr, qr, kr, vt,
        ct, st, 0.125f * 1.4426950408889634f);
    k_attn<<<dim3(8, 64), 256, 0, stream>>>(qr, kr, vt, ob);
    k_gemm_bt<2><<<dim3(DM / 128, TOK / 128), 256, 0, stream>>>(
        ob, woutt, TOK, DM, DM, out, nullptr, nullptr, nullptr,
        nullptr, nullptr, 0.0f);
}